// Round 2
// baseline (616.324 us; speedup 1.0000x reference)
//
#include <hip/hip_runtime.h>
#include <hip/hip_bf16.h>
#include <cstdint>
#include <cstddef>

// LinOSS block: B=32, T=4096, H=256, S=256, M = B*T = 131072
// v2: GEMMs restructured as "W-in-LDS, stream-X" with swapped MFMA operands
// (W as A-op, X as B-op) so the output comes out n-major per lane ->
// vectorized epilogue loads/stores. One barrier per block, no k-loop drains.

typedef __bf16 bf16x8 __attribute__((ext_vector_type(8)));
typedef __bf16 bf16x4 __attribute__((ext_vector_type(4)));
typedef float  f32x4  __attribute__((ext_vector_type(4)));

#define BB 32
#define TT 4096
#define HH 256
#define SS 256
#define MTOT (BB*TT)          // 131072
#define NCHUNK 64
#define CLEN 64               // TT / NCHUNK

__device__ __forceinline__ void gl_lds16(const void* g, void* l) {
    __builtin_amdgcn_global_load_lds((const __attribute__((address_space(1))) void*)g,
                                     (__attribute__((address_space(3))) void*)l, 16, 0, 0);
}

// ---------------- prep: weight cast + coeff ----------------
__global__ void prep_kernel(const float* __restrict__ w1, const float* __restrict__ w2,
                            const float* __restrict__ w3,
                            __bf16* __restrict__ w1b, __bf16* __restrict__ w2b,
                            __bf16* __restrict__ w3b,
                            const float* __restrict__ a_diag, const float* __restrict__ g_diag,
                            const float* __restrict__ dt,
                            float* __restrict__ coeff, float* __restrict__ cL) {
    int i = blockIdx.x * 256 + threadIdx.x;   // 65536 threads = one per weight elem
    w1b[i] = (__bf16)w1[i];
    w2b[i] = (__bf16)w2[i];
    w3b[i] = (__bf16)w3[i];
    if (i < SS) {
        float d = dt[i];
        float sp = (d > 20.f) ? d : log1pf(expf(d));      // softplus
        float dts = sp + 1e-4f;
        float omega = a_diag[i] * dts;
        float gg = g_diag[i];
        float spg = (gg > 20.f) ? gg : log1pf(expf(gg));
        float dec = expf(-spg * dts);
        float c = dec * dec * cosf(omega);
        coeff[i] = c;
        float p = c;
        #pragma unroll
        for (int q = 0; q < 6; ++q) p = p * p;            // c^64
        cL[i] = p;
    }
}

// ---------------- LayerNorm ----------------
__global__ __launch_bounds__(256) void ln_kernel(const float* __restrict__ x,
                          const float* __restrict__ w, const float* __restrict__ b,
                          __bf16* __restrict__ xn) {
    int row = blockIdx.x * 4 + (threadIdx.x >> 6);
    int lane = threadIdx.x & 63;
    size_t base = (size_t)row * HH + lane * 4;
    const float4 v = *(const float4*)&x[base];
    float s  = v.x + v.y + v.z + v.w;
    float ss = v.x*v.x + v.y*v.y + v.z*v.z + v.w*v.w;
    #pragma unroll
    for (int off = 32; off; off >>= 1) {
        s  += __shfl_xor(s,  off, 64);
        ss += __shfl_xor(ss, off, 64);
    }
    float mu  = s * (1.f/256.f);
    float var = ss * (1.f/256.f) - mu*mu;
    float sc  = rsqrtf(var + 1e-5f);
    const float4 wv = *(const float4*)&w[lane*4];
    const float4 bv = *(const float4*)&b[lane*4];
    union { __bf16 h[4]; uint2 u; } pk;
    pk.h[0] = (__bf16)((v.x - mu)*sc*wv.x + bv.x);
    pk.h[1] = (__bf16)((v.y - mu)*sc*wv.y + bv.y);
    pk.h[2] = (__bf16)((v.z - mu)*sc*wv.z + bv.z);
    pk.h[3] = (__bf16)((v.w - mu)*sc*wv.w + bv.w);
    *(uint2*)&xn[base] = pk.u;
}

// ---------------- GEMM v2: C[m,n] = sum_k X[m,k]*W[n,k] + epilogue ----------------
// Block: 256 threads (4 waves). LDS holds a 128-row half of W (64 KB), XOR-swizzled
// per 16B granule to break the 512B-row-stride bank pattern. Each wave streams
// 128 m-rows (4 double-strips of 32) of X straight from global into B-op
// fragments. MFMA(W-frag, X-frag) gives D[n][m]: per-lane regs = 4 consecutive n
// at fixed m -> vectorized epilogue.
template<int MODE>
__global__ __launch_bounds__(256, 2) void gemm_kernel(
    const __bf16* __restrict__ W,   // [256][256] row-major (out x in)
    const __bf16* __restrict__ X,   // [M][256]
    void* Cout,                     // MODE0: bf16 u; MODE1: bf16 mixed (aliases xn_in); MODE2: f32 y
    const __bf16* xn_in,            // MODE1: x_norm (same buffer as Cout)
    const float* __restrict__ dvec, // MODE1: direct[H]
    const float* __restrict__ xres, // MODE2: x
    const float* __restrict__ bias) // MODE2: out_b
{
    __shared__ __bf16 Ws[128 * 256];   // 64 KB
    const int tid  = threadIdx.x;
    const int lane = tid & 63;
    const int wid  = tid >> 6;          // 0..3
    const int l15  = lane & 15, quad = lane >> 4;
    const int half = blockIdx.x & 1;          // n-half
    const int mblk = blockIdx.x >> 1;         // 0..255, 512 rows each

    // stage W rows [half*128, half*128+128) with per-row granule swizzle:
    // lds granule (r,c) holds source k-granule c ^ (r&31)
    #pragma unroll
    for (int it = 0; it < 16; ++it) {
        int g = it * 256 + tid;          // 0..4095 granules of 16 B
        int r = g >> 5, c = g & 31;
        int kc = c ^ (r & 31);
        gl_lds16(W + (size_t)(half * 128 + r) * 256 + kc * 8, &Ws[g * 8]);
    }
    __syncthreads();

    const int mwave = mblk * 512 + wid * 128;

    #pragma unroll 1
    for (int d = 0; d < 4; ++d) {
        const int m0 = mwave + d * 32;
        // load X fragments for 2 strips of 16 rows (B-operand: lane->row, quad->k)
        bf16x8 bf[2][8];
        #pragma unroll
        for (int s = 0; s < 2; ++s)
            #pragma unroll
            for (int kk = 0; kk < 8; ++kk)
                bf[s][kk] = *(const bf16x8*)&X[(size_t)(m0 + s * 16 + l15) * 256 + kk * 32 + quad * 8];

        f32x4 acc[2][8] = {};
        #pragma unroll
        for (int j = 0; j < 8; ++j) {
            const int row = j * 16 + l15;          // W row (local to half)
            #pragma unroll
            for (int kk = 0; kk < 8; ++kk) {
                bf16x8 af = *(const bf16x8*)&Ws[row * 256 + (((kk * 4 + quad) ^ (row & 31)) * 8)];
                acc[0][j] = __builtin_amdgcn_mfma_f32_16x16x32_bf16(af, bf[0][kk], acc[0][j], 0, 0, 0);
                acc[1][j] = __builtin_amdgcn_mfma_f32_16x16x32_bf16(af, bf[1][kk], acc[1][j], 0, 0, 0);
            }
        }

        // epilogue: per (strip, j): lane holds n = half*128+j*16+quad*4 .. +3 at m fixed
        #pragma unroll
        for (int s = 0; s < 2; ++s) {
            #pragma unroll
            for (int j = 0; j < 8; ++j) {
                const int m = m0 + s * 16 + l15;
                const int n = half * 128 + j * 16 + quad * 4;
                const size_t idx = (size_t)m * 256 + n;
                f32x4 v = acc[s][j];
                if (MODE == 0) {
                    bf16x4 pk;
                    #pragma unroll
                    for (int r = 0; r < 4; ++r) pk[r] = (__bf16)v[r];
                    *(bf16x4*)((__bf16*)Cout + idx) = pk;
                } else if (MODE == 1) {
                    bf16x4 xv = *(const bf16x4*)&xn_in[idx];
                    f32x4 dv = *(const f32x4*)&dvec[n];
                    bf16x4 pk;
                    #pragma unroll
                    for (int r = 0; r < 4; ++r) {
                        float t = v[r] + dv[r] * (float)xv[r];
                        float th = tanhf(0.7978845608028654f * (t + 0.044715f * t * t * t));
                        pk[r] = (__bf16)(0.5f * t * (1.0f + th));
                    }
                    *(bf16x4*)((__bf16*)Cout + idx) = pk;
                } else {
                    f32x4 xr = *(const f32x4*)&xres[idx];
                    f32x4 bv = *(const f32x4*)&bias[n];
                    #pragma unroll
                    for (int r = 0; r < 4; ++r) v[r] += xr[r] + bv[r];
                    *(f32x4*)((float*)Cout + idx) = v;
                }
            }
        }
    }
}

// ---------------- scan pass 1: per-chunk carries (read-only on u) ----------------
__global__ __launch_bounds__(256) void scan_carries(const __bf16* __restrict__ u,
                             const float* __restrict__ coeff,
                             const float* __restrict__ state0, float* __restrict__ carry) {
    int ch = blockIdx.x, b = blockIdx.y, s = threadIdx.x;
    float c = coeff[s];
    float st = (ch == 0) ? state0[b * SS + s] : 0.f;
    size_t base = ((size_t)b * TT + (size_t)ch * CLEN) * SS + s;
    #pragma unroll 8
    for (int i = 0; i < CLEN; ++i)
        st = c * st + (float)u[base + (size_t)i * SS];
    carry[(b * NCHUNK + ch) * SS + s] = st;
}

// ---------------- scan pass 2: prefix over chunk carries ----------------
__global__ __launch_bounds__(256) void scan_prefix(float* carry, const float* __restrict__ cL,
                            float* __restrict__ fs_out) {
    int b = blockIdx.x, s = threadIdx.x;
    float cl = cL[s];
    float P = 0.f;
    for (int j = 0; j < NCHUNK; ++j) {
        int idx = (b * NCHUNK + j) * SS + s;
        P = cl * P + carry[idx];
        carry[idx] = P;     // inclusive prefix = state at end of chunk j
    }
    fs_out[b * SS + s] = P; // final_state (t = T-1)
}

// ---------------- scan pass 3: apply (in-place u -> states) ----------------
__global__ __launch_bounds__(256) void scan_apply(__bf16* u, const float* __restrict__ coeff,
                           const float* __restrict__ state0,
                           const float* __restrict__ carry) {
    int ch = blockIdx.x, b = blockIdx.y, s = threadIdx.x;
    float c = coeff[s];
    float st = (ch == 0) ? state0[b * SS + s]
                         : carry[(b * NCHUNK + ch - 1) * SS + s];
    size_t base = ((size_t)b * TT + (size_t)ch * CLEN) * SS + s;
    #pragma unroll 8
    for (int i = 0; i < CLEN; ++i) {
        st = c * st + (float)u[base + (size_t)i * SS];
        u[base + (size_t)i * SS] = (__bf16)st;
    }
}

extern "C" void kernel_launch(void* const* d_in, const int* in_sizes, int n_in,
                              void* d_out, int out_size, void* d_ws, size_t ws_size,
                              hipStream_t stream) {
    const float* x      = (const float*)d_in[0];
    const float* state0 = (const float*)d_in[1];
    const float* w1     = (const float*)d_in[2];   // in_to_state [S,H]
    const float* w2     = (const float*)d_in[3];   // state_to_hidden [H,S]
    const float* direct = (const float*)d_in[4];
    const float* a_diag = (const float*)d_in[5];
    const float* g_diag = (const float*)d_in[6];
    const float* dt     = (const float*)d_in[7];
    const float* norm_w = (const float*)d_in[8];
    const float* norm_b = (const float*)d_in[9];
    const float* w3     = (const float*)d_in[10];  // out_w [H,H]
    const float* out_b  = (const float*)d_in[11];

    char* ws = (char*)d_ws;
    const size_t MH2 = (size_t)MTOT * HH * 2;      // 67108864
    __bf16* xn    = (__bf16*)(ws);                  // [M,H] bf16 (later holds mixed)
    __bf16* u     = (__bf16*)(ws + MH2);            // [M,S] bf16 (u -> states)
    __bf16* w1b   = (__bf16*)(ws + 2*MH2);
    __bf16* w2b   = (__bf16*)(ws + 2*MH2 + 131072);
    __bf16* w3b   = (__bf16*)(ws + 2*MH2 + 262144);
    float*  coeff = (float*)(ws + 2*MH2 + 393216);
    float*  cL    = (float*)(ws + 2*MH2 + 394240);
    float*  carry = (float*)(ws + 2*MH2 + 395264);  // [B, NCHUNK, S] f32 = 2MB

    float* y_out  = (float*)d_out;
    float* fs_out = (float*)d_out + (size_t)MTOT * HH;

    prep_kernel<<<256, 256, 0, stream>>>(w1, w2, w3, w1b, w2b, w3b,
                                         a_diag, g_diag, dt, coeff, cL);
    ln_kernel<<<MTOT/4, 256, 0, stream>>>(x, norm_w, norm_b, xn);
    gemm_kernel<0><<<512, 256, 0, stream>>>(w1b, xn, u, nullptr, nullptr, nullptr, nullptr);
    scan_carries<<<dim3(NCHUNK, BB), 256, 0, stream>>>(u, coeff, state0, carry);
    scan_prefix<<<BB, 256, 0, stream>>>(carry, cL, fs_out);
    scan_apply<<<dim3(NCHUNK, BB), 256, 0, stream>>>(u, coeff, state0, carry);
    gemm_kernel<1><<<512, 256, 0, stream>>>(w2b, u, xn, xn, direct, nullptr, nullptr);
    gemm_kernel<2><<<512, 256, 0, stream>>>(w3b, xn, y_out, nullptr, nullptr, x, out_b);
}

// Round 3
// 429.803 us; speedup vs baseline: 1.4340x; 1.4340x over previous
//
#include <hip/hip_runtime.h>
#include <hip/hip_bf16.h>
#include <cstdint>
#include <cstddef>

// LinOSS block: B=32, T=4096, H=256, S=256, M = B*T = 131072
// v3 GEMM: full-N blocks (X fetched once), W entirely in VGPRs (128/wave),
// LDS = 32KB swizzled X staging + 32KB swizzled epilogue transpose buffer.
// All global traffic is wave-contiguous (>=1KB/instr). Prefetch issued
// right after a barrier so the vmcnt(0)-before-barrier drain is always
// covered by a full compute phase.

typedef __bf16 bf16x8 __attribute__((ext_vector_type(8)));
typedef __bf16 bf16x4 __attribute__((ext_vector_type(4)));
typedef float  f32x4  __attribute__((ext_vector_type(4)));
typedef unsigned int u32x4 __attribute__((ext_vector_type(4)));

#define BB 32
#define TT 4096
#define HH 256
#define SS 256
#define MTOT (BB*TT)          // 131072
#define NCHUNK 64
#define CLEN 64               // TT / NCHUNK
#define NT 8                  // m-tiles (64 rows) per block

// ---------------- prep: weight cast + coeff ----------------
__global__ void prep_kernel(const float* __restrict__ w1, const float* __restrict__ w2,
                            const float* __restrict__ w3,
                            __bf16* __restrict__ w1b, __bf16* __restrict__ w2b,
                            __bf16* __restrict__ w3b,
                            const float* __restrict__ a_diag, const float* __restrict__ g_diag,
                            const float* __restrict__ dt,
                            float* __restrict__ coeff, float* __restrict__ cL) {
    int i = blockIdx.x * 256 + threadIdx.x;   // 65536 threads = one per weight elem
    w1b[i] = (__bf16)w1[i];
    w2b[i] = (__bf16)w2[i];
    w3b[i] = (__bf16)w3[i];
    if (i < SS) {
        float d = dt[i];
        float sp = (d > 20.f) ? d : log1pf(expf(d));      // softplus
        float dts = sp + 1e-4f;
        float omega = a_diag[i] * dts;
        float gg = g_diag[i];
        float spg = (gg > 20.f) ? gg : log1pf(expf(gg));
        float dec = expf(-spg * dts);
        float c = dec * dec * cosf(omega);
        coeff[i] = c;
        float p = c;
        #pragma unroll
        for (int q = 0; q < 6; ++q) p = p * p;            // c^64
        cL[i] = p;
    }
}

// ---------------- LayerNorm ----------------
__global__ __launch_bounds__(256) void ln_kernel(const float* __restrict__ x,
                          const float* __restrict__ w, const float* __restrict__ b,
                          __bf16* __restrict__ xn) {
    int row = blockIdx.x * 4 + (threadIdx.x >> 6);
    int lane = threadIdx.x & 63;
    size_t base = (size_t)row * HH + lane * 4;
    const float4 v = *(const float4*)&x[base];
    float s  = v.x + v.y + v.z + v.w;
    float ss = v.x*v.x + v.y*v.y + v.z*v.z + v.w*v.w;
    #pragma unroll
    for (int off = 32; off; off >>= 1) {
        s  += __shfl_xor(s,  off, 64);
        ss += __shfl_xor(ss, off, 64);
    }
    float mu  = s * (1.f/256.f);
    float var = ss * (1.f/256.f) - mu*mu;
    float sc  = rsqrtf(var + 1e-5f);
    const float4 wv = *(const float4*)&w[lane*4];
    const float4 bv = *(const float4*)&b[lane*4];
    union { __bf16 h[4]; uint2 u; } pk;
    pk.h[0] = (__bf16)((v.x - mu)*sc*wv.x + bv.x);
    pk.h[1] = (__bf16)((v.y - mu)*sc*wv.y + bv.y);
    pk.h[2] = (__bf16)((v.z - mu)*sc*wv.z + bv.z);
    pk.h[3] = (__bf16)((v.w - mu)*sc*wv.w + bv.w);
    *(uint2*)&xn[base] = pk.u;
}

// ---------------- GEMM v3 ----------------
// C[m,n] = sum_k X[m,k] * W[n,k], M=131072, N=K=256.
// Block: 512 threads = 8 waves as 2(m) x 4(n). Wave tile: 32m x 64n.
// W frags (A-operand, n=rows) in VGPRs: 4 n-strips x 8 k = 32 frags = 128 VGPR.
// X staged in swizzled LDS (32KB/tile of 64 rows), frags read as B-operand.
// Epilogue: acc -> swizzled Es (bf16) -> coalesced bf16x8 rows -> mode math ->
// contiguous global stores.
template<int MODE>
__global__ __launch_bounds__(512, 2) void gemm_kernel(
    const __bf16* __restrict__ W,   // [256][256] row-major (n x k)
    const __bf16* __restrict__ X,   // [M][256]
    void* Cout,                     // MODE0: bf16 u; MODE1: bf16 mixed (aliases xn_in); MODE2: f32 y
    const __bf16* xn_in,            // MODE1: x_norm (same buffer as Cout)
    const float* __restrict__ dvec, // MODE1: direct[H]
    const float* __restrict__ xres, // MODE2: x
    const float* __restrict__ bias) // MODE2: out_b
{
    __shared__ __bf16 Xs[64 * 256];   // 32 KB, 16B-granule swizzle g^(m&15)
    __shared__ __bf16 Es[64 * 256];   // 32 KB, 8B-granule swizzle g^((m&15)<<2)

    const int tid  = threadIdx.x;
    const int lane = tid & 63;
    const int wid  = tid >> 6;          // 0..7
    const int l15  = lane & 15, quad = lane >> 4;
    const int wn   = wid >> 1;          // 0..3  (n-group of 64)
    const int wm   = wid & 1;           // 0..1  (m-group of 32)

    // ---- W fragments (read once; W is L2/L3-hot: 256 blocks x 128KB) ----
    bf16x8 Wf[4][8];
    #pragma unroll
    for (int jn = 0; jn < 4; ++jn) {
        const int n = wn * 64 + jn * 16 + l15;
        #pragma unroll
        for (int kb = 0; kb < 8; ++kb)
            Wf[jn][kb] = *(const bf16x8*)&W[(size_t)n * 256 + kb * 32 + quad * 8];
    }

    // ---- staging geometry (per-thread constants) ----
    int srow[4], scol[4], sdst[4];
    #pragma unroll
    for (int j = 0; j < 4; ++j) {
        int o = wid * 256 + j * 64 + lane;   // 16B granule id within 64x256 tile
        int m = o >> 5, g = o & 31;
        srow[j] = m;
        scol[j] = g * 8;
        sdst[j] = m * 512 + ((g ^ (m & 15)) * 16);
    }

    const size_t mbase = (size_t)blockIdx.x * (64 * NT);

    u32x4 pf[4];
    // stage tile 0
    #pragma unroll
    for (int j = 0; j < 4; ++j)
        pf[j] = *(const u32x4*)&X[(mbase + srow[j]) * 256 + scol[j]];
    #pragma unroll
    for (int j = 0; j < 4; ++j)
        *(u32x4*)((char*)Xs + sdst[j]) = pf[j];
    __syncthreads();
    // prefetch tile 1 (in flight across MFMA phase of tile 0)
    #pragma unroll
    for (int j = 0; j < 4; ++j)
        pf[j] = *(const u32x4*)&X[(mbase + 64 + srow[j]) * 256 + scol[j]];

    const int mrow0 = wm * 32 + l15;         // im=0 fragment row
    const int hrow  = tid >> 5;              // 0..15 (epilogue row-in-group)
    const int nc    = tid & 31;              // 16B chunk within row

    for (int it = 0; it < NT; ++it) {
        const size_t mt0 = mbase + (size_t)it * 64;

        // ---- MFMA phase on tile it ----
        f32x4 acc[2][4] = {};
        #pragma unroll
        for (int kb = 0; kb < 8; ++kb) {
            bf16x8 xf[2];
            #pragma unroll
            for (int im = 0; im < 2; ++im) {
                int m = mrow0 + im * 16;
                xf[im] = *(const bf16x8*)((char*)Xs + m * 512 + (((kb * 4 + quad) ^ l15) * 16));
            }
            #pragma unroll
            for (int jn = 0; jn < 4; ++jn)
                #pragma unroll
                for (int im = 0; im < 2; ++im)
                    acc[im][jn] = __builtin_amdgcn_mfma_f32_16x16x32_bf16(
                        Wf[jn][kb], xf[im], acc[im][jn], 0, 0, 0);
        }
        __syncthreads();   // A: Xs reads done; prefetch (issued a full phase ago) drains free

        // ---- write next tile into Xs; dump acc into Es (bf16) ----
        if (it + 1 < NT) {
            #pragma unroll
            for (int j = 0; j < 4; ++j)
                *(u32x4*)((char*)Xs + sdst[j]) = pf[j];
        }
        #pragma unroll
        for (int im = 0; im < 2; ++im) {
            const int m = mrow0 + im * 16;
            #pragma unroll
            for (int jn = 0; jn < 4; ++jn) {
                const int gn = wn * 16 + jn * 4 + quad;     // 8B granule (= n>>2)
                bf16x4 pk;
                #pragma unroll
                for (int r = 0; r < 4; ++r) pk[r] = (__bf16)acc[im][jn][r];
                *(bf16x4*)((char*)Es + m * 512 + ((gn ^ (l15 << 2)) * 8)) = pk;
            }
        }
        __syncthreads();   // E: Es + Xs(it+1) ready; only old stores outstanding (cheap)

        // ---- prefetch tile it+2 (right after barrier -> never drained early) ----
        if (it + 2 < NT) {
            #pragma unroll
            for (int j = 0; j < 4; ++j)
                pf[j] = *(const u32x4*)&X[(mt0 + 128 + srow[j]) * 256 + scol[j]];
        }

        // ---- coalesced store phase: 4 rounds x 16 rows ----
        #pragma unroll
        for (int r = 0; r < 4; ++r) {
            const int m = r * 16 + hrow;
            bf16x8 ev = *(const bf16x8*)((char*)Es + m * 512 + (((nc * 2) ^ (hrow << 2)) * 8));
            const size_t gidx = (mt0 + m) * 256 + nc * 8;
            if (MODE == 0) {
                *(bf16x8*)((__bf16*)Cout + gidx) = ev;
            } else if (MODE == 1) {
                bf16x8 xv = *(const bf16x8*)&xn_in[gidx];
                f32x4 d0 = *(const f32x4*)&dvec[nc * 8];
                f32x4 d1 = *(const f32x4*)&dvec[nc * 8 + 4];
                bf16x8 pk;
                #pragma unroll
                for (int j = 0; j < 8; ++j) {
                    float dj = (j < 4) ? d0[j] : d1[j - 4];
                    float t = (float)ev[j] + dj * (float)xv[j];
                    float th = tanhf(0.7978845608028654f * (t + 0.044715f * t * t * t));
                    pk[j] = (__bf16)(0.5f * t * (1.0f + th));
                }
                *(bf16x8*)((__bf16*)Cout + gidx) = pk;
            } else {
                f32x4 x0 = *(const f32x4*)&xres[gidx];
                f32x4 x1 = *(const f32x4*)&xres[gidx + 4];
                f32x4 b0 = *(const f32x4*)&bias[nc * 8];
                f32x4 b1 = *(const f32x4*)&bias[nc * 8 + 4];
                f32x4 y0, y1;
                #pragma unroll
                for (int j = 0; j < 4; ++j) {
                    y0[j] = x0[j] + (float)ev[j]     + b0[j];
                    y1[j] = x1[j] + (float)ev[j + 4] + b1[j];
                }
                *(f32x4*)((float*)Cout + gidx)     = y0;
                *(f32x4*)((float*)Cout + gidx + 4) = y1;
            }
        }
    }
}

// ---------------- scan pass 1: per-chunk carries (read-only on u) ----------------
__global__ __launch_bounds__(256) void scan_carries(const __bf16* __restrict__ u,
                             const float* __restrict__ coeff,
                             const float* __restrict__ state0, float* __restrict__ carry) {
    int ch = blockIdx.x, b = blockIdx.y, s = threadIdx.x;
    float c = coeff[s];
    float st = (ch == 0) ? state0[b * SS + s] : 0.f;
    size_t base = ((size_t)b * TT + (size_t)ch * CLEN) * SS + s;
    #pragma unroll 8
    for (int i = 0; i < CLEN; ++i)
        st = c * st + (float)u[base + (size_t)i * SS];
    carry[(b * NCHUNK + ch) * SS + s] = st;
}

// ---------------- scan pass 2: prefix over chunk carries ----------------
__global__ __launch_bounds__(256) void scan_prefix(float* carry, const float* __restrict__ cL,
                            float* __restrict__ fs_out) {
    int b = blockIdx.x, s = threadIdx.x;
    float cl = cL[s];
    float P = 0.f;
    for (int j = 0; j < NCHUNK; ++j) {
        int idx = (b * NCHUNK + j) * SS + s;
        P = cl * P + carry[idx];
        carry[idx] = P;     // inclusive prefix = state at end of chunk j
    }
    fs_out[b * SS + s] = P; // final_state (t = T-1)
}

// ---------------- scan pass 3: apply (in-place u -> states) ----------------
__global__ __launch_bounds__(256) void scan_apply(__bf16* u, const float* __restrict__ coeff,
                           const float* __restrict__ state0,
                           const float* __restrict__ carry) {
    int ch = blockIdx.x, b = blockIdx.y, s = threadIdx.x;
    float c = coeff[s];
    float st = (ch == 0) ? state0[b * SS + s]
                         : carry[(b * NCHUNK + ch - 1) * SS + s];
    size_t base = ((size_t)b * TT + (size_t)ch * CLEN) * SS + s;
    #pragma unroll 8
    for (int i = 0; i < CLEN; ++i) {
        st = c * st + (float)u[base + (size_t)i * SS];
        u[base + (size_t)i * SS] = (__bf16)st;
    }
}

extern "C" void kernel_launch(void* const* d_in, const int* in_sizes, int n_in,
                              void* d_out, int out_size, void* d_ws, size_t ws_size,
                              hipStream_t stream) {
    const float* x      = (const float*)d_in[0];
    const float* state0 = (const float*)d_in[1];
    const float* w1     = (const float*)d_in[2];   // in_to_state [S,H]
    const float* w2     = (const float*)d_in[3];   // state_to_hidden [H,S]
    const float* direct = (const float*)d_in[4];
    const float* a_diag = (const float*)d_in[5];
    const float* g_diag = (const float*)d_in[6];
    const float* dt     = (const float*)d_in[7];
    const float* norm_w = (const float*)d_in[8];
    const float* norm_b = (const float*)d_in[9];
    const float* w3     = (const float*)d_in[10];  // out_w [H,H]
    const float* out_b  = (const float*)d_in[11];

    char* ws = (char*)d_ws;
    const size_t MH2 = (size_t)MTOT * HH * 2;      // 67108864
    __bf16* xn    = (__bf16*)(ws);                  // [M,H] bf16 (later holds mixed)
    __bf16* u     = (__bf16*)(ws + MH2);            // [M,S] bf16 (u -> states)
    __bf16* w1b   = (__bf16*)(ws + 2*MH2);
    __bf16* w2b   = (__bf16*)(ws + 2*MH2 + 131072);
    __bf16* w3b   = (__bf16*)(ws + 2*MH2 + 262144);
    float*  coeff = (float*)(ws + 2*MH2 + 393216);
    float*  cL    = (float*)(ws + 2*MH2 + 394240);
    float*  carry = (float*)(ws + 2*MH2 + 395264);  // [B, NCHUNK, S] f32 = 2MB

    float* y_out  = (float*)d_out;
    float* fs_out = (float*)d_out + (size_t)MTOT * HH;

    prep_kernel<<<256, 256, 0, stream>>>(w1, w2, w3, w1b, w2b, w3b,
                                         a_diag, g_diag, dt, coeff, cL);
    ln_kernel<<<MTOT/4, 256, 0, stream>>>(x, norm_w, norm_b, xn);
    gemm_kernel<0><<<256, 512, 0, stream>>>(w1b, xn, u, nullptr, nullptr, nullptr, nullptr);
    scan_carries<<<dim3(NCHUNK, BB), 256, 0, stream>>>(u, coeff, state0, carry);
    scan_prefix<<<BB, 256, 0, stream>>>(carry, cL, fs_out);
    scan_apply<<<dim3(NCHUNK, BB), 256, 0, stream>>>(u, coeff, state0, carry);
    gemm_kernel<1><<<256, 512, 0, stream>>>(w2b, u, xn, xn, direct, nullptr, nullptr);
    gemm_kernel<2><<<256, 512, 0, stream>>>(w3b, xn, y_out, nullptr, nullptr, x, out_b);
}